// Round 10
// baseline (1325.102 us; speedup 1.0000x reference)
//
#include <hip/hip_runtime.h>

#define HID 128
#define G3  384   // 3*HID
#define TSTEPS 5
#define BSHIFT 9          // 512 nodes per bucket
#define BNODES (1 << BSHIFT)
#define MAXBUK 256        // supports N up to 128k
#define PART_EPB 8192     // edges per k_part block

typedef unsigned int  uint;
typedef unsigned short ushort;

typedef float  f32x4  __attribute__((ext_vector_type(4)));
typedef __bf16 bf16x8 __attribute__((ext_vector_type(8)));

union B8u { uint4 u; bf16x8 b; ushort s[8]; };

static __device__ inline ushort f2bf(float f) {
  uint u = __float_as_uint(f);
  uint r = u + 0x7fffu + ((u >> 16) & 1u);   // RTN-even
  return (ushort)(r >> 16);
}
static __device__ inline float bf2f(ushort s) {
  return __uint_as_float(((uint)s) << 16);
}

// ---- once per call: W_comb = W_ih @ W_e (bf16), bvec = W_ih @ b_e, W_hh -> bf16
__global__ __launch_bounds__(128) void k_weights(
    const float* __restrict__ W_e, const float* __restrict__ b_e,
    const float* __restrict__ W_ih, const float* __restrict__ W_hh,
    ushort* __restrict__ Wcomb, ushort* __restrict__ Whh16, float* __restrict__ bvec)
{
  int j = blockIdx.x, t = threadIdx.x;
  if (j < G3) {
    __shared__ float row[HID];
    row[t] = W_ih[j * HID + t];
    __syncthreads();
    float acc = 0.f;
    for (int k = 0; k < HID; ++k) acc = fmaf(row[k], W_e[k * HID + t], acc);
    Wcomb[j * HID + t] = f2bf(acc);
    if (t == 0) {
      float b = 0.f;
      for (int k = 0; k < HID; ++k) b += row[k] * b_e[k];
      bvec[j] = b;
    }
  } else {
    int j2 = j - G3;
    Whh16[j2 * HID + t] = f2bf(W_hh[j2 * HID + t]);
  }
}

// ---- CSR build, stage 1: bucket histogram of dst (LDS-aggregated)
__global__ __launch_bounds__(256) void k_bh(const int* __restrict__ dst,
                                            int* __restrict__ bhist, int E) {
  __shared__ int lh[MAXBUK];
  int t = threadIdx.x;
  if (t < MAXBUK) lh[t] = 0;
  __syncthreads();
  for (int e = blockIdx.x * 256 + t; e < E; e += gridDim.x * 256)
    atomicAdd(&lh[dst[e] >> BSHIFT], 1);
  __syncthreads();
  if (t < MAXBUK && lh[t]) atomicAdd(&bhist[t], lh[t]);
}

// ---- stage 2: serial scan of <=256 bucket counts (trivial size)
__global__ __launch_bounds__(256) void k_bsc(const int* __restrict__ bhist,
                                             int* __restrict__ bbase,
                                             int* __restrict__ gcur,
                                             int* __restrict__ rowptr, int E, int N) {
  __shared__ int ls[MAXBUK];
  int t = threadIdx.x;
  ls[t] = bhist[t];
  __syncthreads();
  if (t == 0) {
    int run = 0;
    for (int i = 0; i < MAXBUK; ++i) {
      bbase[i] = run; gcur[i] = run; run += ls[i];
    }
    bbase[MAXBUK] = run;
    rowptr[N] = E;
  }
}

// ---- stage 3: partition packed (dl<<20)|src into bucket-grouped ebuf.
__global__ __launch_bounds__(256) void k_part(
    const int* __restrict__ src, const int* __restrict__ dst,
    int* __restrict__ gcur, uint* __restrict__ ebuf, int E) {
  __shared__ int lh[MAXBUK], lbase[MAXBUK], lcur[MAXBUK];
  int t = threadIdx.x;
  int base = blockIdx.x * PART_EPB;
  if (t < MAXBUK) lh[t] = 0;
  __syncthreads();
#pragma unroll 4
  for (int j = 0; j < PART_EPB / 256; ++j) {
    int e = base + j * 256 + t;
    if (e < E) atomicAdd(&lh[dst[e] >> BSHIFT], 1);
  }
  __syncthreads();
  if (t < MAXBUK) {
    lbase[t] = lh[t] ? atomicAdd(&gcur[t], lh[t]) : 0;
    lcur[t] = 0;
  }
  __syncthreads();
#pragma unroll 4
  for (int j = 0; j < PART_EPB / 256; ++j) {
    int e = base + j * 256 + t;
    if (e < E) {
      int d = dst[e];
      int b = d >> BSHIFT;
      int p = atomicAdd(&lcur[b], 1);
      ebuf[lbase[b] + p] = (uint)src[e] | ((uint)(d & (BNODES - 1)) << 20);
    }
  }
}

// ---- stage 4: one block per bucket: LDS hist -> scan -> rowptr/deg -> scatter
__global__ __launch_bounds__(256) void k_fill2(
    const uint* __restrict__ ebuf, const int* __restrict__ bbase,
    int* __restrict__ csrc, int* __restrict__ rowptr, int* __restrict__ deg, int N) {
  __shared__ int hcnt[BNODES];
  __shared__ int wls[4];
  int t = threadIdx.x;
  int b = blockIdx.x;
  int ebeg = bbase[b], eend = bbase[b + 1];
  for (int i = t; i < BNODES; i += 256) hcnt[i] = 0;
  __syncthreads();
  for (int e = ebeg + t; e < eend; e += 256)
    atomicAdd(&hcnt[ebuf[e] >> 20], 1);
  __syncthreads();
  const int PER = BNODES / 256;
  int lane = t & 63, wv = t >> 6;
  int x[PER]; int s = 0;
#pragma unroll
  for (int i = 0; i < PER; ++i) { x[i] = hcnt[PER * t + i]; s += x[i]; }
  int incl = s;
#pragma unroll
  for (int off = 1; off < 64; off <<= 1) {
    int u = __shfl_up(incl, off, 64);
    if (lane >= off) incl += u;
  }
  if (lane == 63) wls[wv] = incl;
  __syncthreads();
  int wbase = 0;
  for (int i = 0; i < wv; ++i) wbase += wls[i];
  int run = wbase + incl - s;
#pragma unroll
  for (int i = 0; i < PER; ++i) {
    int node = (b << BSHIFT) + PER * t + i;
    hcnt[PER * t + i] = run;
    if (node < N) { rowptr[node] = ebeg + run; deg[node] = x[i]; }
    run += x[i];
  }
  __syncthreads();
  for (int e = ebeg + t; e < eend; e += 256) {
    uint v = ebuf[e];
    int p = atomicAdd(&hcnt[v >> 20], 1);
    csrc[ebeg + p] = (int)(v & 0xFFFFFu);
  }
}

__global__ void k_init(const float* __restrict__ m, ushort* __restrict__ hb, int N) {
  int idx = blockIdx.x * 256 + threadIdx.x;
  if (idx >= N * HID) return;
  int d = idx & (HID - 1);
  float v = (d == 0) ? m[idx >> 7] : 0.f;
  hb[idx] = f2bf(v);
}

// ---- FUSED message-pass + GRU step. Block = 8 waves over a 16-node strip
// (grid-stride). Phase A: each wave gathers 2 nodes (4 edge slots x 16
// dim-chunks) and stages 2 hbc rows, writing bf16 results into LDS tiles in
// MFMA-fragment order (chunk-major, stride 17 uint4 -> benign bank pattern).
// One barrier. Phase B: ds_read A/H frags, per-kc weight loads from L2
// (non-persistent -> VGPR<=128 -> 2 blocks/CU so one block's gather overlaps
// the other's MFMA), GRU epilogue -> hbn row-major.
__global__ __launch_bounds__(512, 4) void k_step(
    const int* __restrict__ rowptr, const int* __restrict__ csrc,
    const ushort* __restrict__ hbc, ushort* __restrict__ hbn,
    const ushort* __restrict__ Wcomb, const ushort* __restrict__ Whh16,
    const float* __restrict__ bvec, const float* __restrict__ b_ih,
    const float* __restrict__ b_hh, const int* __restrict__ deg,
    int N, int nstrip)
{
  __shared__ uint4 tile[2][2][272];   // [buf][0=hsum,1=h][chunk*17 + row]
  const int w = threadIdx.x >> 6;
  const int lane = threadIdx.x & 63;
  const int g = lane >> 4;            // edge slot (A) / quad (B)
  const int i = lane & 15;            // chunk (A) / row l16 (B)
  const int d = w * 16 + i;           // output dim owned in phase B

  const float bir = b_ih[d], biz = b_ih[d + 128], bin_ = b_ih[d + 256];
  const float bhr = b_hh[d], bhz = b_hh[d + 128], bhn = b_hh[d + 256];
  const float vr = bvec[d], vz = bvec[d + 128], vn = bvec[d + 256];

  auto phaseA = [&](int ss, int pp) {
    int n0 = ss << 4;
    if (g < 2) {                      // stage this wave's 2 h rows
      int r = 2 * w + g;
      tile[pp][1][i * 17 + r] = *(const uint4*)(hbc + (size_t)(n0 + r) * HID + i * 8);
    }
#pragma unroll
    for (int k = 0; k < 2; ++k) {
      int v = n0 + 2 * w + k;
      int beg = rowptr[v], end = rowptr[v + 1];
      float acc[8] = {0.f, 0.f, 0.f, 0.f, 0.f, 0.f, 0.f, 0.f};
      int e = beg;
      for (; e + 16 <= end; e += 16) {
        int s0 = csrc[e + g];
        int s1 = csrc[e + 4 + g];
        int s2 = csrc[e + 8 + g];
        int s3 = csrc[e + 12 + g];
        B8u w0; w0.u = *(const uint4*)(hbc + (size_t)s0 * HID + i * 8);
        B8u w1; w1.u = *(const uint4*)(hbc + (size_t)s1 * HID + i * 8);
        B8u w2; w2.u = *(const uint4*)(hbc + (size_t)s2 * HID + i * 8);
        B8u w3; w3.u = *(const uint4*)(hbc + (size_t)s3 * HID + i * 8);
#pragma unroll
        for (int j = 0; j < 8; ++j)
          acc[j] += (bf2f(w0.s[j]) + bf2f(w1.s[j])) + (bf2f(w2.s[j]) + bf2f(w3.s[j]));
      }
      for (; e < end; e += 4) {
        int ee = e + g;
        if (ee < end) {
          int s0 = csrc[ee];
          B8u w0; w0.u = *(const uint4*)(hbc + (size_t)s0 * HID + i * 8);
#pragma unroll
          for (int j = 0; j < 8; ++j) acc[j] += bf2f(w0.s[j]);
        }
      }
#pragma unroll
      for (int j = 0; j < 8; ++j) {
        acc[j] += __shfl_xor(acc[j], 16, 64);
        acc[j] += __shfl_xor(acc[j], 32, 64);
      }
      if (g == 0) {
        uint4 ov;
        ov.x = ((uint)f2bf(acc[1]) << 16) | (uint)f2bf(acc[0]);
        ov.y = ((uint)f2bf(acc[3]) << 16) | (uint)f2bf(acc[2]);
        ov.z = ((uint)f2bf(acc[5]) << 16) | (uint)f2bf(acc[4]);
        ov.w = ((uint)f2bf(acc[7]) << 16) | (uint)f2bf(acc[6]);
        tile[pp][0][i * 17 + (2 * w + k)] = ov;
      }
    }
  };

  auto phaseB = [&](int ss, int pp) {
    int n0 = ss << 4;
    f32x4 acc[6] = {};
#pragma unroll
    for (int kc = 0; kc < 4; ++kc) {
      B8u af; af.u = tile[pp][0][(kc * 4 + g) * 17 + i];
      B8u hf; hf.u = tile[pp][1][(kc * 4 + g) * 17 + i];
#pragma unroll
      for (int gg = 0; gg < 3; ++gg) {
        int j = (w * 16 + gg * 128 + i) * HID + kc * 32 + g * 8;
        B8u bw; bw.u = *(const uint4*)(Wcomb + j);
        acc[gg] = __builtin_amdgcn_mfma_f32_16x16x32_bf16(af.b, bw.b, acc[gg], 0, 0, 0);
        B8u bh; bh.u = *(const uint4*)(Whh16 + j);
        acc[3 + gg] = __builtin_amdgcn_mfma_f32_16x16x32_bf16(hf.b, bh.b, acc[3 + gg], 0, 0, 0);
      }
    }
    const ushort* hbt = (const ushort*)&tile[pp][1][0];
    int c0 = 2 * w + (i >> 3);
#pragma unroll
    for (int rg = 0; rg < 4; ++rg) {
      int row = g * 4 + rg;
      float hold = bf2f(hbt[c0 * 136 + row * 8 + (i & 7)]);
      float degf = (float)deg[n0 + row];
      float ir = acc[0][rg] + degf * vr + bir;
      float iz = acc[1][rg] + degf * vz + biz;
      float in_ = acc[2][rg] + degf * vn + bin_;
      float hr = acc[3][rg] + bhr;
      float hz = acc[4][rg] + bhz;
      float hn = acc[5][rg] + bhn;
      float r = __builtin_amdgcn_rcpf(1.f + __expf(-(ir + hr)));
      float z = __builtin_amdgcn_rcpf(1.f + __expf(-(iz + hz)));
      float x2 = in_ + r * hn;
      float e2 = __expf(2.f * x2);
      float nv = 1.f - 2.f * __builtin_amdgcn_rcpf(e2 + 1.f);   // tanh
      float hv = (1.f - z) * nv + z * hold;
      hbn[(size_t)(n0 + row) * HID + d] = f2bf(hv);
    }
  };

  int s = blockIdx.x;
  if (s >= nstrip) return;
  int p = 0;
  phaseA(s, p);
  while (true) {
    __syncthreads();        // LDS writes of A(s) visible; buf p^1 free (all done B(s-1))
    phaseB(s, p);
    int ns = s + (int)gridDim.x;
    if (ns >= nstrip) break;
    s = ns; p ^= 1;
    phaseA(s, p);
  }
}

// ---- per-graph counts from SORTED gid: binary search, no atomics
__global__ __launch_bounds__(64) void k_bounds(const int* __restrict__ gid,
                                               int* __restrict__ cnt, int N, int G) {
  int g = threadIdx.x;
  if (g >= G) return;
  int lo = 0, hi = N;
  while (lo < hi) { int mid = (lo + hi) >> 1; if (gid[mid] < g) lo = mid + 1; else hi = mid; }
  int lb0 = lo;
  lo = 0; hi = N;
  int g1 = g + 1;
  while (lo < hi) { int mid = (lo + hi) >> 1; if (gid[mid] < g1) lo = mid + 1; else hi = mid; }
  cnt[g] = lo - lb0;
}

// ---- pooling: graph_ids sorted -> run-length accumulate, few atomics
#define POOL_CHUNK 96
__global__ __launch_bounds__(128) void k_pool(const ushort* __restrict__ hb,
                                              const int* __restrict__ gid,
                                              float* __restrict__ hg, int N) {
  int d = threadIdx.x;
  int start = blockIdx.x * POOL_CHUNK;
  if (start >= N) return;
  int end = min(start + POOL_CHUNK, N);
  float acc = 0.f;
  int g = gid[start];
  for (int n = start; n < end; ++n) {
    int gn = gid[n];
    if (gn != g) { unsafeAtomicAdd(&hg[g * HID + d], acc); acc = 0.f; g = gn; }
    acc += fmaxf(bf2f(hb[(size_t)n * HID + d]), 0.f);   // relu
  }
  unsafeAtomicAdd(&hg[g * HID + d], acc);
}

__global__ __launch_bounds__(640) void k_cls(const float* __restrict__ hg,
                                             const int* __restrict__ cnt,
                                             const float* __restrict__ Wc,
                                             const float* __restrict__ bc,
                                             float* __restrict__ out, int G) {
  int t = threadIdx.x;
  if (t >= G * 10) return;
  int g = t / 10, c = t % 10;
  float inv = 1.f / fmaxf((float)cnt[g], 1.f);
  float acc = 0.f;
  for (int d = 0; d < HID; ++d) acc = fmaf(hg[g * HID + d], Wc[c * HID + d], acc);
  out[t] = acc * inv + bc[c];
}

extern "C" void kernel_launch(void* const* d_in, const int* in_sizes, int n_in,
                              void* d_out, int out_size, void* d_ws, size_t ws_size,
                              hipStream_t stream) {
  const int N = in_sizes[0];
  const int E = in_sizes[9];
  const float* m    = (const float*)d_in[0];
  const float* W_e  = (const float*)d_in[1];
  const float* b_e  = (const float*)d_in[2];
  const float* W_ih = (const float*)d_in[3];
  const float* b_ih = (const float*)d_in[4];
  const float* W_hh = (const float*)d_in[5];
  const float* b_hh = (const float*)d_in[6];
  const float* W_cls = (const float*)d_in[7];
  const float* b_cls = (const float*)d_in[8];
  const int* src = (const int*)d_in[9];
  const int* dst = (const int*)d_in[10];
  const int* gid = (const int*)d_in[11];
  const int G = out_size / 10;
  float* out = (float*)d_out;

  size_t off = 0;
  auto alloc = [&](size_t b) {
    char* p = (char*)d_ws + off;
    off += (b + 255) & ~(size_t)255;
    return (void*)p;
  };
  ushort* hb0    = (ushort*)alloc((size_t)N * HID * 2);
  ushort* hb1    = (ushort*)alloc((size_t)N * HID * 2);
  int*    deg    = (int*)   alloc((size_t)N * 4);
  int*    rowptr = (int*)   alloc((size_t)(N + 1) * 4);
  int*    csrc   = (int*)   alloc((size_t)E * 4);
  uint*   ebuf   = (uint*)  alloc((size_t)E * 4);
  int*    bhist  = (int*)   alloc((size_t)MAXBUK * 4);
  int*    bbase  = (int*)   alloc((size_t)(MAXBUK + 1) * 4);
  int*    gcur   = (int*)   alloc((size_t)MAXBUK * 4);
  ushort* Wcomb  = (ushort*)alloc((size_t)G3 * HID * 2);
  ushort* Whh16  = (ushort*)alloc((size_t)G3 * HID * 2);
  float*  bvec   = (float*) alloc((size_t)G3 * 4);
  float*  hg     = (float*) alloc((size_t)G * HID * 4);
  int*    cnt    = (int*)   alloc((size_t)G * 4);
  if (off > ws_size) return;   // workspace too small -> visible failure

  const int NBUK = (N + BNODES - 1) >> BSHIFT;   // 196 at N=100k (<= MAXBUK)

  k_weights<<<2 * G3, HID, 0, stream>>>(W_e, b_e, W_ih, W_hh, Wcomb, Whh16, bvec);
  hipMemsetAsync(bhist, 0, (size_t)MAXBUK * 4, stream);
  k_bh<<<256, 256, 0, stream>>>(dst, bhist, E);
  k_bsc<<<1, MAXBUK, 0, stream>>>(bhist, bbase, gcur, rowptr, E, N);
  k_part<<<(E + PART_EPB - 1) / PART_EPB, 256, 0, stream>>>(src, dst, gcur, ebuf, E);
  k_fill2<<<NBUK, 256, 0, stream>>>(ebuf, bbase, csrc, rowptr, deg, N);
  k_init<<<(N * HID + 255) / 256, 256, 0, stream>>>(m, hb0, N);

  ushort* hbc = hb0;
  ushort* hbn = hb1;
  const int nstrip = N >> 4;
  int blocks = nstrip < 2048 ? nstrip : 2048;
  for (int s = 0; s < TSTEPS; ++s) {
    k_step<<<blocks, 512, 0, stream>>>(rowptr, csrc, hbc, hbn, Wcomb, Whh16,
                                       bvec, b_ih, b_hh, deg, N, nstrip);
    ushort* t = hbc; hbc = hbn; hbn = t;
  }

  hipMemsetAsync(hg, 0, (size_t)G * HID * 4, stream);
  k_bounds<<<1, 64, 0, stream>>>(gid, cnt, N, G);
  k_pool<<<(N + POOL_CHUNK - 1) / POOL_CHUNK, HID, 0, stream>>>(hbc, gid, hg, N);
  k_cls<<<1, 640, 0, stream>>>(hg, cnt, W_cls, b_cls, out, G);
}

// Round 11
// 1239.000 us; speedup vs baseline: 1.0695x; 1.0695x over previous
//
#include <hip/hip_runtime.h>

#define HID 128
#define G3  384   // 3*HID
#define TSTEPS 5
#define BSHIFT 9          // 512 nodes per bucket
#define BNODES (1 << BSHIFT)
#define MAXBUK 256        // supports N up to 128k
#define PART_EPB 8192     // edges per k_part block

typedef unsigned int  uint;
typedef unsigned short ushort;

typedef float  f32x4  __attribute__((ext_vector_type(4)));
typedef __bf16 bf16x8 __attribute__((ext_vector_type(8)));

union B8u { uint4 u; bf16x8 b; ushort s[8]; };

static __device__ inline ushort f2bf(float f) {
  uint u = __float_as_uint(f);
  uint r = u + 0x7fffu + ((u >> 16) & 1u);   // RTN-even
  return (ushort)(r >> 16);
}
static __device__ inline float bf2f(ushort s) {
  return __uint_as_float(((uint)s) << 16);
}

// ---- once per call: W_comb = W_ih @ W_e (bf16), bvec = W_ih @ b_e, W_hh -> bf16
__global__ __launch_bounds__(128) void k_weights(
    const float* __restrict__ W_e, const float* __restrict__ b_e,
    const float* __restrict__ W_ih, const float* __restrict__ W_hh,
    ushort* __restrict__ Wcomb, ushort* __restrict__ Whh16, float* __restrict__ bvec)
{
  int j = blockIdx.x, t = threadIdx.x;
  if (j < G3) {
    __shared__ float row[HID];
    row[t] = W_ih[j * HID + t];
    __syncthreads();
    float acc = 0.f;
    for (int k = 0; k < HID; ++k) acc = fmaf(row[k], W_e[k * HID + t], acc);
    Wcomb[j * HID + t] = f2bf(acc);
    if (t == 0) {
      float b = 0.f;
      for (int k = 0; k < HID; ++k) b += row[k] * b_e[k];
      bvec[j] = b;
    }
  } else {
    int j2 = j - G3;
    Whh16[j2 * HID + t] = f2bf(W_hh[j2 * HID + t]);
  }
}

// ---- CSR build, stage 1: bucket histogram of dst (LDS-aggregated)
__global__ __launch_bounds__(256) void k_bh(const int* __restrict__ dst,
                                            int* __restrict__ bhist, int E) {
  __shared__ int lh[MAXBUK];
  int t = threadIdx.x;
  if (t < MAXBUK) lh[t] = 0;
  __syncthreads();
  for (int e = blockIdx.x * 256 + t; e < E; e += gridDim.x * 256)
    atomicAdd(&lh[dst[e] >> BSHIFT], 1);
  __syncthreads();
  if (t < MAXBUK && lh[t]) atomicAdd(&bhist[t], lh[t]);
}

// ---- stage 2: serial scan of <=256 bucket counts (trivial size)
__global__ __launch_bounds__(256) void k_bsc(const int* __restrict__ bhist,
                                             int* __restrict__ bbase,
                                             int* __restrict__ gcur,
                                             int* __restrict__ rowptr, int E, int N) {
  __shared__ int ls[MAXBUK];
  int t = threadIdx.x;
  ls[t] = bhist[t];
  __syncthreads();
  if (t == 0) {
    int run = 0;
    for (int i = 0; i < MAXBUK; ++i) {
      bbase[i] = run; gcur[i] = run; run += ls[i];
    }
    bbase[MAXBUK] = run;
    rowptr[N] = E;
  }
}

// ---- stage 3: partition packed (dl<<20)|src into bucket-grouped ebuf.
__global__ __launch_bounds__(256) void k_part(
    const int* __restrict__ src, const int* __restrict__ dst,
    int* __restrict__ gcur, uint* __restrict__ ebuf, int E) {
  __shared__ int lh[MAXBUK], lbase[MAXBUK], lcur[MAXBUK];
  int t = threadIdx.x;
  int base = blockIdx.x * PART_EPB;
  if (t < MAXBUK) lh[t] = 0;
  __syncthreads();
#pragma unroll 4
  for (int j = 0; j < PART_EPB / 256; ++j) {
    int e = base + j * 256 + t;
    if (e < E) atomicAdd(&lh[dst[e] >> BSHIFT], 1);
  }
  __syncthreads();
  if (t < MAXBUK) {
    lbase[t] = lh[t] ? atomicAdd(&gcur[t], lh[t]) : 0;
    lcur[t] = 0;
  }
  __syncthreads();
#pragma unroll 4
  for (int j = 0; j < PART_EPB / 256; ++j) {
    int e = base + j * 256 + t;
    if (e < E) {
      int d = dst[e];
      int b = d >> BSHIFT;
      int p = atomicAdd(&lcur[b], 1);
      ebuf[lbase[b] + p] = (uint)src[e] | ((uint)(d & (BNODES - 1)) << 20);
    }
  }
}

// ---- stage 4: one block per bucket: LDS hist -> scan -> rowptr/deg -> scatter
__global__ __launch_bounds__(256) void k_fill2(
    const uint* __restrict__ ebuf, const int* __restrict__ bbase,
    int* __restrict__ csrc, int* __restrict__ rowptr, int* __restrict__ deg, int N) {
  __shared__ int hcnt[BNODES];
  __shared__ int wls[4];
  int t = threadIdx.x;
  int b = blockIdx.x;
  int ebeg = bbase[b], eend = bbase[b + 1];
  for (int i = t; i < BNODES; i += 256) hcnt[i] = 0;
  __syncthreads();
  for (int e = ebeg + t; e < eend; e += 256)
    atomicAdd(&hcnt[ebuf[e] >> 20], 1);
  __syncthreads();
  const int PER = BNODES / 256;
  int lane = t & 63, wv = t >> 6;
  int x[PER]; int s = 0;
#pragma unroll
  for (int i = 0; i < PER; ++i) { x[i] = hcnt[PER * t + i]; s += x[i]; }
  int incl = s;
#pragma unroll
  for (int off = 1; off < 64; off <<= 1) {
    int u = __shfl_up(incl, off, 64);
    if (lane >= off) incl += u;
  }
  if (lane == 63) wls[wv] = incl;
  __syncthreads();
  int wbase = 0;
  for (int i = 0; i < wv; ++i) wbase += wls[i];
  int run = wbase + incl - s;
#pragma unroll
  for (int i = 0; i < PER; ++i) {
    int node = (b << BSHIFT) + PER * t + i;
    hcnt[PER * t + i] = run;
    if (node < N) { rowptr[node] = ebeg + run; deg[node] = x[i]; }
    run += x[i];
  }
  __syncthreads();
  for (int e = ebeg + t; e < eend; e += 256) {
    uint v = ebuf[e];
    int p = atomicAdd(&hcnt[v >> 20], 1);
    csrc[ebeg + p] = (int)(v & 0xFFFFFu);
  }
}

__global__ void k_init(const float* __restrict__ m, ushort* __restrict__ hb, int N) {
  int idx = blockIdx.x * 256 + threadIdx.x;
  if (idx >= N * HID) return;
  int d = idx & (HID - 1);
  float v = (d == 0) ? m[idx >> 7] : 0.f;
  hb[idx] = f2bf(v);
}

// ---- gather: hs16[v] = bf16( sum_{u in N_in(v)} h[u] ); one wave per node.
__global__ __launch_bounds__(256) void k_gather(
    const int* __restrict__ rowptr, const int* __restrict__ csrc,
    const ushort* __restrict__ hb, ushort* __restrict__ hs16, int N)
{
  int v = blockIdx.x * 4 + (threadIdx.x >> 6);
  if (v >= N) return;
  int lane = threadIdx.x & 63;
  int g = lane >> 4;        // edge slot 0..3
  int i = lane & 15;        // 16B chunk of row
  int beg = rowptr[v], end = rowptr[v + 1];
  float acc[8] = {0.f, 0.f, 0.f, 0.f, 0.f, 0.f, 0.f, 0.f};
  int e = beg;
  for (; e + 16 <= end; e += 16) {      // 16 edges in flight
    int s0 = csrc[e + g];
    int s1 = csrc[e + 4 + g];
    int s2 = csrc[e + 8 + g];
    int s3 = csrc[e + 12 + g];
    B8u w0; w0.u = *(const uint4*)(hb + (size_t)s0 * HID + i * 8);
    B8u w1; w1.u = *(const uint4*)(hb + (size_t)s1 * HID + i * 8);
    B8u w2; w2.u = *(const uint4*)(hb + (size_t)s2 * HID + i * 8);
    B8u w3; w3.u = *(const uint4*)(hb + (size_t)s3 * HID + i * 8);
#pragma unroll
    for (int j = 0; j < 8; ++j)
      acc[j] += (bf2f(w0.s[j]) + bf2f(w1.s[j])) + (bf2f(w2.s[j]) + bf2f(w3.s[j]));
  }
  for (; e < end; e += 4) {             // predicated 4-edge tail
    int ee = e + g;
    if (ee < end) {
      int s0 = csrc[ee];
      B8u w; w.u = *(const uint4*)(hb + (size_t)s0 * HID + i * 8);
#pragma unroll
      for (int j = 0; j < 8; ++j) acc[j] += bf2f(w.s[j]);
    }
  }
#pragma unroll
  for (int j = 0; j < 8; ++j) {
    acc[j] += __shfl_xor(acc[j], 16, 64);
    acc[j] += __shfl_xor(acc[j], 32, 64);
  }
  if (g == 0) {
    uint4 ov;
    ov.x = ((uint)f2bf(acc[1]) << 16) | (uint)f2bf(acc[0]);
    ov.y = ((uint)f2bf(acc[3]) << 16) | (uint)f2bf(acc[2]);
    ov.z = ((uint)f2bf(acc[5]) << 16) | (uint)f2bf(acc[4]);
    ov.w = ((uint)f2bf(acc[7]) << 16) | (uint)f2bf(acc[6]);
    *(uint4*)(hs16 + (size_t)v * HID + i * 8) = ov;
  }
}

// ---- fused GEMM + GRU. NON-persistent weights: fragments re-loaded from L2
// per strip (weights = 196 KB, L2-resident; no gather stream competing in
// this kernel). Caps regs via __launch_bounds__(512,4) -> 4 waves/SIMD,
// 2 blocks/CU: TLP hides A-load + weight-load latency. hb ping-pongs
// across steps; no barriers.
__global__ __launch_bounds__(512, 4) void k_gru(
    const ushort* __restrict__ hs16,
    const ushort* __restrict__ hbc, ushort* __restrict__ hbn,
    const ushort* __restrict__ Wcomb, const ushort* __restrict__ Whh16,
    const float* __restrict__ bvec, const float* __restrict__ b_ih,
    const float* __restrict__ b_hh, const int* __restrict__ deg, int N)
{
  const int w = threadIdx.x >> 6;
  const int lane = threadIdx.x & 63;
  const int quad = lane >> 4, l16 = lane & 15;
  const int d0 = w * 16;
  const int d = d0 + l16;

  const float bir = b_ih[d], biz = b_ih[d + 128], bin_ = b_ih[d + 256];
  const float bhr = b_hh[d], bhz = b_hh[d + 128], bhn = b_hh[d + 256];
  const float vr = bvec[d], vz = bvec[d + 128], vn = bvec[d + 256];

  const int nstrip = N >> 4;
  for (int s = blockIdx.x; s < nstrip; s += (int)gridDim.x) {
    int n0 = s << 4;
    size_t arow = (size_t)(n0 + l16) * HID + quad * 8;
    B8u af[4], hf[4];
#pragma unroll
    for (int kc = 0; kc < 4; ++kc) {
      af[kc].u = *(const uint4*)(hs16 + arow + kc * 32);
      hf[kc].u = *(const uint4*)(hbc + arow + kc * 32);
    }
    float hold[4], degf[4];
#pragma unroll
    for (int rg = 0; rg < 4; ++rg) {
      int n = n0 + quad * 4 + rg;
      hold[rg] = bf2f(hbc[(size_t)n * HID + d]);
      degf[rg] = (float)deg[n];
    }

    f32x4 acc[6] = {};
#pragma unroll
    for (int kc = 0; kc < 4; ++kc)
#pragma unroll
      for (int g = 0; g < 3; ++g) {
        int j = (d0 + g * 128 + l16) * HID + kc * 32 + quad * 8;
        B8u bw; bw.u = *(const uint4*)(Wcomb + j);
        acc[g] = __builtin_amdgcn_mfma_f32_16x16x32_bf16(af[kc].b, bw.b, acc[g], 0, 0, 0);
        B8u bh; bh.u = *(const uint4*)(Whh16 + j);
        acc[3 + g] = __builtin_amdgcn_mfma_f32_16x16x32_bf16(hf[kc].b, bh.b, acc[3 + g], 0, 0, 0);
      }

#pragma unroll
    for (int rg = 0; rg < 4; ++rg) {
      float ir = acc[0][rg] + degf[rg] * vr + bir;
      float iz = acc[1][rg] + degf[rg] * vz + biz;
      float in_ = acc[2][rg] + degf[rg] * vn + bin_;
      float hr = acc[3][rg] + bhr;
      float hz = acc[4][rg] + bhz;
      float hn = acc[5][rg] + bhn;
      float r = __builtin_amdgcn_rcpf(1.f + __expf(-(ir + hr)));
      float z = __builtin_amdgcn_rcpf(1.f + __expf(-(iz + hz)));
      float x2 = in_ + r * hn;
      float e2 = __expf(2.f * x2);
      float nv = 1.f - 2.f * __builtin_amdgcn_rcpf(e2 + 1.f);   // tanh
      float hv = (1.f - z) * nv + z * hold[rg];
      hbn[(size_t)(n0 + quad * 4 + rg) * HID + d] = f2bf(hv);
    }
  }
}

// ---- per-graph counts from SORTED gid: binary search, no atomics
__global__ __launch_bounds__(64) void k_bounds(const int* __restrict__ gid,
                                               int* __restrict__ cnt, int N, int G) {
  int g = threadIdx.x;
  if (g >= G) return;
  int lo = 0, hi = N;
  while (lo < hi) { int mid = (lo + hi) >> 1; if (gid[mid] < g) lo = mid + 1; else hi = mid; }
  int lb0 = lo;
  lo = 0; hi = N;
  int g1 = g + 1;
  while (lo < hi) { int mid = (lo + hi) >> 1; if (gid[mid] < g1) lo = mid + 1; else hi = mid; }
  cnt[g] = lo - lb0;
}

// ---- pooling: graph_ids sorted -> run-length accumulate, few atomics
#define POOL_CHUNK 96
__global__ __launch_bounds__(128) void k_pool(const ushort* __restrict__ hb,
                                              const int* __restrict__ gid,
                                              float* __restrict__ hg, int N) {
  int d = threadIdx.x;
  int start = blockIdx.x * POOL_CHUNK;
  if (start >= N) return;
  int end = min(start + POOL_CHUNK, N);
  float acc = 0.f;
  int g = gid[start];
  for (int n = start; n < end; ++n) {
    int gn = gid[n];
    if (gn != g) { unsafeAtomicAdd(&hg[g * HID + d], acc); acc = 0.f; g = gn; }
    acc += fmaxf(bf2f(hb[(size_t)n * HID + d]), 0.f);   // relu
  }
  unsafeAtomicAdd(&hg[g * HID + d], acc);
}

__global__ __launch_bounds__(640) void k_cls(const float* __restrict__ hg,
                                             const int* __restrict__ cnt,
                                             const float* __restrict__ Wc,
                                             const float* __restrict__ bc,
                                             float* __restrict__ out, int G) {
  int t = threadIdx.x;
  if (t >= G * 10) return;
  int g = t / 10, c = t % 10;
  float inv = 1.f / fmaxf((float)cnt[g], 1.f);
  float acc = 0.f;
  for (int d = 0; d < HID; ++d) acc = fmaf(hg[g * HID + d], Wc[c * HID + d], acc);
  out[t] = acc * inv + bc[c];
}

extern "C" void kernel_launch(void* const* d_in, const int* in_sizes, int n_in,
                              void* d_out, int out_size, void* d_ws, size_t ws_size,
                              hipStream_t stream) {
  const int N = in_sizes[0];
  const int E = in_sizes[9];
  const float* m    = (const float*)d_in[0];
  const float* W_e  = (const float*)d_in[1];
  const float* b_e  = (const float*)d_in[2];
  const float* W_ih = (const float*)d_in[3];
  const float* b_ih = (const float*)d_in[4];
  const float* W_hh = (const float*)d_in[5];
  const float* b_hh = (const float*)d_in[6];
  const float* W_cls = (const float*)d_in[7];
  const float* b_cls = (const float*)d_in[8];
  const int* src = (const int*)d_in[9];
  const int* dst = (const int*)d_in[10];
  const int* gid = (const int*)d_in[11];
  const int G = out_size / 10;
  float* out = (float*)d_out;

  size_t off = 0;
  auto alloc = [&](size_t b) {
    char* p = (char*)d_ws + off;
    off += (b + 255) & ~(size_t)255;
    return (void*)p;
  };
  ushort* hb0    = (ushort*)alloc((size_t)N * HID * 2);
  ushort* hb1    = (ushort*)alloc((size_t)N * HID * 2);
  ushort* hs16   = (ushort*)alloc((size_t)N * HID * 2);
  int*    deg    = (int*)   alloc((size_t)N * 4);
  int*    rowptr = (int*)   alloc((size_t)(N + 1) * 4);
  int*    csrc   = (int*)   alloc((size_t)E * 4);
  uint*   ebuf   = (uint*)  alloc((size_t)E * 4);
  int*    bhist  = (int*)   alloc((size_t)MAXBUK * 4);
  int*    bbase  = (int*)   alloc((size_t)(MAXBUK + 1) * 4);
  int*    gcur   = (int*)   alloc((size_t)MAXBUK * 4);
  ushort* Wcomb  = (ushort*)alloc((size_t)G3 * HID * 2);
  ushort* Whh16  = (ushort*)alloc((size_t)G3 * HID * 2);
  float*  bvec   = (float*) alloc((size_t)G3 * 4);
  float*  hg     = (float*) alloc((size_t)G * HID * 4);
  int*    cnt    = (int*)   alloc((size_t)G * 4);
  if (off > ws_size) return;   // workspace too small -> visible failure

  const int NBUK = (N + BNODES - 1) >> BSHIFT;   // 196 at N=100k (<= MAXBUK)

  k_weights<<<2 * G3, HID, 0, stream>>>(W_e, b_e, W_ih, W_hh, Wcomb, Whh16, bvec);
  hipMemsetAsync(bhist, 0, (size_t)MAXBUK * 4, stream);
  k_bh<<<256, 256, 0, stream>>>(dst, bhist, E);
  k_bsc<<<1, MAXBUK, 0, stream>>>(bhist, bbase, gcur, rowptr, E, N);
  k_part<<<(E + PART_EPB - 1) / PART_EPB, 256, 0, stream>>>(src, dst, gcur, ebuf, E);
  k_fill2<<<NBUK, 256, 0, stream>>>(ebuf, bbase, csrc, rowptr, deg, N);
  k_init<<<(N * HID + 255) / 256, 256, 0, stream>>>(m, hb0, N);

  ushort* hbc = hb0;
  ushort* hbn = hb1;
  const int nstrip = N >> 4;
  int blocks = nstrip < 2048 ? nstrip : 2048;
  for (int s = 0; s < TSTEPS; ++s) {
    k_gather<<<(N + 3) / 4, 256, 0, stream>>>(rowptr, csrc, hbc, hs16, N);
    k_gru<<<blocks, 512, 0, stream>>>(hs16, hbc, hbn, Wcomb, Whh16, bvec, b_ih, b_hh, deg, N);
    ushort* t = hbc; hbc = hbn; hbn = t;
  }

  hipMemsetAsync(hg, 0, (size_t)G * HID * 4, stream);
  k_bounds<<<1, 64, 0, stream>>>(gid, cnt, N, G);
  k_pool<<<(N + POOL_CHUNK - 1) / POOL_CHUNK, HID, 0, stream>>>(hbc, gid, hg, N);
  k_cls<<<1, 640, 0, stream>>>(hg, cnt, W_cls, b_cls, out, G);
}

// Round 12
// 927.335 us; speedup vs baseline: 1.4289x; 1.3361x over previous
//
#include <hip/hip_runtime.h>

#define HID 128
#define G3  384   // 3*HID
#define TSTEPS 5
#define BSHIFT 9          // 512 nodes per bucket
#define BNODES (1 << BSHIFT)
#define MAXBUK 256        // supports N up to 128k
#define PART_EPB 8192     // edges per k_part block

typedef unsigned int  uint;
typedef unsigned short ushort;

typedef float  f32x4  __attribute__((ext_vector_type(4)));
typedef __bf16 bf16x8 __attribute__((ext_vector_type(8)));

union B8u { uint4 u; bf16x8 b; ushort s[8]; };

static __device__ inline ushort f2bf(float f) {
  uint u = __float_as_uint(f);
  uint r = u + 0x7fffu + ((u >> 16) & 1u);   // RTN-even
  return (ushort)(r >> 16);
}
static __device__ inline float bf2f(ushort s) {
  return __uint_as_float(((uint)s) << 16);
}

// ---- once per call: W_comb = W_ih @ W_e (bf16), bvec = W_ih @ b_e, W_hh -> bf16
__global__ __launch_bounds__(128) void k_weights(
    const float* __restrict__ W_e, const float* __restrict__ b_e,
    const float* __restrict__ W_ih, const float* __restrict__ W_hh,
    ushort* __restrict__ Wcomb, ushort* __restrict__ Whh16, float* __restrict__ bvec)
{
  int j = blockIdx.x, t = threadIdx.x;
  if (j < G3) {
    __shared__ float row[HID];
    row[t] = W_ih[j * HID + t];
    __syncthreads();
    float acc = 0.f;
    for (int k = 0; k < HID; ++k) acc = fmaf(row[k], W_e[k * HID + t], acc);
    Wcomb[j * HID + t] = f2bf(acc);
    if (t == 0) {
      float b = 0.f;
      for (int k = 0; k < HID; ++k) b += row[k] * b_e[k];
      bvec[j] = b;
    }
  } else {
    int j2 = j - G3;
    Whh16[j2 * HID + t] = f2bf(W_hh[j2 * HID + t]);
  }
}

// ---- CSR build, stage 1: bucket histogram of dst (LDS-aggregated)
__global__ __launch_bounds__(256) void k_bh(const int* __restrict__ dst,
                                            int* __restrict__ bhist, int E) {
  __shared__ int lh[MAXBUK];
  int t = threadIdx.x;
  if (t < MAXBUK) lh[t] = 0;
  __syncthreads();
  for (int e = blockIdx.x * 256 + t; e < E; e += gridDim.x * 256)
    atomicAdd(&lh[dst[e] >> BSHIFT], 1);
  __syncthreads();
  if (t < MAXBUK && lh[t]) atomicAdd(&bhist[t], lh[t]);
}

// ---- stage 2: serial scan of <=256 bucket counts (trivial size)
__global__ __launch_bounds__(256) void k_bsc(const int* __restrict__ bhist,
                                             int* __restrict__ bbase,
                                             int* __restrict__ gcur,
                                             int* __restrict__ rowptr, int E, int N) {
  __shared__ int ls[MAXBUK];
  int t = threadIdx.x;
  ls[t] = bhist[t];
  __syncthreads();
  if (t == 0) {
    int run = 0;
    for (int i = 0; i < MAXBUK; ++i) {
      bbase[i] = run; gcur[i] = run; run += ls[i];
    }
    bbase[MAXBUK] = run;
    rowptr[N] = E;
  }
}

// ---- stage 3: partition packed (dl<<20)|src into bucket-grouped ebuf.
__global__ __launch_bounds__(256) void k_part(
    const int* __restrict__ src, const int* __restrict__ dst,
    int* __restrict__ gcur, uint* __restrict__ ebuf, int E) {
  __shared__ int lh[MAXBUK], lbase[MAXBUK], lcur[MAXBUK];
  int t = threadIdx.x;
  int base = blockIdx.x * PART_EPB;
  if (t < MAXBUK) lh[t] = 0;
  __syncthreads();
#pragma unroll 4
  for (int j = 0; j < PART_EPB / 256; ++j) {
    int e = base + j * 256 + t;
    if (e < E) atomicAdd(&lh[dst[e] >> BSHIFT], 1);
  }
  __syncthreads();
  if (t < MAXBUK) {
    lbase[t] = lh[t] ? atomicAdd(&gcur[t], lh[t]) : 0;
    lcur[t] = 0;
  }
  __syncthreads();
#pragma unroll 4
  for (int j = 0; j < PART_EPB / 256; ++j) {
    int e = base + j * 256 + t;
    if (e < E) {
      int d = dst[e];
      int b = d >> BSHIFT;
      int p = atomicAdd(&lcur[b], 1);
      ebuf[lbase[b] + p] = (uint)src[e] | ((uint)(d & (BNODES - 1)) << 20);
    }
  }
}

// ---- stage 4: one block per bucket: LDS hist -> scan -> rowptr/deg -> scatter
__global__ __launch_bounds__(256) void k_fill2(
    const uint* __restrict__ ebuf, const int* __restrict__ bbase,
    int* __restrict__ csrc, int* __restrict__ rowptr, int* __restrict__ deg, int N) {
  __shared__ int hcnt[BNODES];
  __shared__ int wls[4];
  int t = threadIdx.x;
  int b = blockIdx.x;
  int ebeg = bbase[b], eend = bbase[b + 1];
  for (int i = t; i < BNODES; i += 256) hcnt[i] = 0;
  __syncthreads();
  for (int e = ebeg + t; e < eend; e += 256)
    atomicAdd(&hcnt[ebuf[e] >> 20], 1);
  __syncthreads();
  const int PER = BNODES / 256;
  int lane = t & 63, wv = t >> 6;
  int x[PER]; int s = 0;
#pragma unroll
  for (int i = 0; i < PER; ++i) { x[i] = hcnt[PER * t + i]; s += x[i]; }
  int incl = s;
#pragma unroll
  for (int off = 1; off < 64; off <<= 1) {
    int u = __shfl_up(incl, off, 64);
    if (lane >= off) incl += u;
  }
  if (lane == 63) wls[wv] = incl;
  __syncthreads();
  int wbase = 0;
  for (int i = 0; i < wv; ++i) wbase += wls[i];
  int run = wbase + incl - s;
#pragma unroll
  for (int i = 0; i < PER; ++i) {
    int node = (b << BSHIFT) + PER * t + i;
    hcnt[PER * t + i] = run;
    if (node < N) { rowptr[node] = ebeg + run; deg[node] = x[i]; }
    run += x[i];
  }
  __syncthreads();
  for (int e = ebeg + t; e < eend; e += 256) {
    uint v = ebuf[e];
    int p = atomicAdd(&hcnt[v >> 20], 1);
    csrc[ebeg + p] = (int)(v & 0xFFFFFu);
  }
}

__global__ void k_init(const float* __restrict__ m, ushort* __restrict__ hb, int N) {
  int idx = blockIdx.x * 256 + threadIdx.x;
  if (idx >= N * HID) return;
  int d = idx & (HID - 1);
  float v = (d == 0) ? m[idx >> 7] : 0.f;
  hb[idx] = f2bf(v);
}

// ---- gather: hs16[v] = bf16( sum_{u in N_in(v)} h[u] ); one wave per node.
// XCD-aligned block swizzle: strip s is gathered by a block on XCD s%8,
// matching k_gru's consumer (strip s runs on block s%1024, XCD s%8) so the
// hs16 rows written here are L2-local for gru's A-fragment loads.
__global__ __launch_bounds__(256) void k_gather(
    const int* __restrict__ rowptr, const int* __restrict__ csrc,
    const ushort* __restrict__ hb, ushort* __restrict__ hs16, int N, int nstrip)
{
  int x = blockIdx.x & 7;
  int ii = blockIdx.x >> 3;
  int s = 8 * (ii >> 2) + x;          // strip, s%8 == x == our XCD (heuristic)
  if (s >= nstrip) return;
  int v = s * 16 + (ii & 3) * 4 + (threadIdx.x >> 6);
  if (v >= N) return;
  int lane = threadIdx.x & 63;
  int g = lane >> 4;        // edge slot 0..3
  int i = lane & 15;        // 16B chunk of row
  int beg = rowptr[v], end = rowptr[v + 1];
  float acc[8] = {0.f, 0.f, 0.f, 0.f, 0.f, 0.f, 0.f, 0.f};
  int e = beg;
  for (; e + 16 <= end; e += 16) {      // 16 edges in flight
    int s0 = csrc[e + g];
    int s1 = csrc[e + 4 + g];
    int s2 = csrc[e + 8 + g];
    int s3 = csrc[e + 12 + g];
    B8u w0; w0.u = *(const uint4*)(hb + (size_t)s0 * HID + i * 8);
    B8u w1; w1.u = *(const uint4*)(hb + (size_t)s1 * HID + i * 8);
    B8u w2; w2.u = *(const uint4*)(hb + (size_t)s2 * HID + i * 8);
    B8u w3; w3.u = *(const uint4*)(hb + (size_t)s3 * HID + i * 8);
#pragma unroll
    for (int j = 0; j < 8; ++j)
      acc[j] += (bf2f(w0.s[j]) + bf2f(w1.s[j])) + (bf2f(w2.s[j]) + bf2f(w3.s[j]));
  }
  for (; e < end; e += 4) {             // predicated 4-edge tail
    int ee = e + g;
    if (ee < end) {
      int s0 = csrc[ee];
      B8u w; w.u = *(const uint4*)(hb + (size_t)s0 * HID + i * 8);
#pragma unroll
      for (int j = 0; j < 8; ++j) acc[j] += bf2f(w.s[j]);
    }
  }
#pragma unroll
  for (int j = 0; j < 8; ++j) {
    acc[j] += __shfl_xor(acc[j], 16, 64);
    acc[j] += __shfl_xor(acc[j], 32, 64);
  }
  if (g == 0) {
    uint4 ov;
    ov.x = ((uint)f2bf(acc[1]) << 16) | (uint)f2bf(acc[0]);
    ov.y = ((uint)f2bf(acc[3]) << 16) | (uint)f2bf(acc[2]);
    ov.z = ((uint)f2bf(acc[5]) << 16) | (uint)f2bf(acc[4]);
    ov.w = ((uint)f2bf(acc[7]) << 16) | (uint)f2bf(acc[6]);
    *(uint4*)(hs16 + (size_t)v * HID + i * 8) = ov;
  }
}

// ---- fused GEMM + GRU helpers (R9 structure — best measured: 85.7 us/step)
struct GruCtx {
  const ushort* hs16; const ushort* hbc; ushort* hbn; const int* deg;
  int l16, quad, d;
  float bir, biz, bin_, bhr, bhz, bhn, vr, vz, vn;
};

static __device__ __forceinline__ void gru_load(
    const GruCtx& c, int s, B8u af[4], B8u hf[4], float hold[4], float degf[4]) {
  int n0 = s << 4;
  size_t arow = (size_t)(n0 + c.l16) * HID + c.quad * 8;
#pragma unroll
  for (int kc = 0; kc < 4; ++kc) {
    af[kc].u = *(const uint4*)(c.hs16 + arow + kc * 32);
    hf[kc].u = *(const uint4*)(c.hbc + arow + kc * 32);
  }
#pragma unroll
  for (int rg = 0; rg < 4; ++rg) {
    int n = n0 + c.quad * 4 + rg;
    hold[rg] = bf2f(c.hbc[(size_t)n * HID + c.d]);
    degf[rg] = (float)c.deg[n];
  }
}

static __device__ __forceinline__ void gru_compute(
    const GruCtx& c, int s, const B8u af[4], const B8u hf[4],
    const float hold[4], const float degf[4],
    const B8u bw[3][4], const B8u bh[3][4]) {
  f32x4 acc[6] = {};
#pragma unroll
  for (int kc = 0; kc < 4; ++kc)
#pragma unroll
    for (int g = 0; g < 3; ++g) {
      acc[g]     = __builtin_amdgcn_mfma_f32_16x16x32_bf16(af[kc].b, bw[g][kc].b, acc[g], 0, 0, 0);
      acc[3 + g] = __builtin_amdgcn_mfma_f32_16x16x32_bf16(hf[kc].b, bh[g][kc].b, acc[3 + g], 0, 0, 0);
    }
  int n0 = s << 4;
#pragma unroll
  for (int rg = 0; rg < 4; ++rg) {
    float ir = acc[0][rg] + degf[rg] * c.vr + c.bir;
    float iz = acc[1][rg] + degf[rg] * c.vz + c.biz;
    float in_ = acc[2][rg] + degf[rg] * c.vn + c.bin_;
    float hr = acc[3][rg] + c.bhr;
    float hz = acc[4][rg] + c.bhz;
    float hn = acc[5][rg] + c.bhn;
    float r = __builtin_amdgcn_rcpf(1.f + __expf(-(ir + hr)));
    float z = __builtin_amdgcn_rcpf(1.f + __expf(-(iz + hz)));
    float x2 = in_ + r * hn;
    float e2 = __expf(2.f * x2);
    float nv = 1.f - 2.f * __builtin_amdgcn_rcpf(e2 + 1.f);   // tanh
    float hv = (1.f - z) * nv + z * hold[rg];
    c.hbn[(size_t)(n0 + c.quad * 4 + rg) * HID + c.d] = f2bf(hv);
  }
}

// Persistent weights in regs (96 VGPR) + 2-body ping-pong. 1 block/CU by
// register budget — measured faster than every higher-occupancy variant
// (R10 fusion: 235us, R11 non-persistent: 158us, this: 85.7us).
__global__ __launch_bounds__(512, 2) void k_gru(
    const ushort* __restrict__ hs16,
    const ushort* __restrict__ hbc, ushort* __restrict__ hbn,
    const ushort* __restrict__ Wcomb, const ushort* __restrict__ Whh16,
    const float* __restrict__ bvec, const float* __restrict__ b_ih,
    const float* __restrict__ b_hh, const int* __restrict__ deg, int N)
{
  const int w = threadIdx.x >> 6;
  const int lane = threadIdx.x & 63;
  const int quad = lane >> 4, l16 = lane & 15;
  const int d0 = w * 16;
  const int d = d0 + l16;

  B8u bw[3][4], bh[3][4];
#pragma unroll
  for (int g = 0; g < 3; ++g)
#pragma unroll
    for (int kc = 0; kc < 4; ++kc) {
      int j = (d0 + g * 128 + l16) * HID + kc * 32 + quad * 8;
      bw[g][kc].u = *(const uint4*)(Wcomb + j);
      bh[g][kc].u = *(const uint4*)(Whh16 + j);
    }

  GruCtx c;
  c.hs16 = hs16; c.hbc = hbc; c.hbn = hbn; c.deg = deg;
  c.l16 = l16; c.quad = quad; c.d = d;
  c.bir = b_ih[d]; c.biz = b_ih[d + 128]; c.bin_ = b_ih[d + 256];
  c.bhr = b_hh[d]; c.bhz = b_hh[d + 128]; c.bhn = b_hh[d + 256];
  c.vr = bvec[d]; c.vz = bvec[d + 128]; c.vn = bvec[d + 256];

  const int nstrip = N >> 4;
  const int G = (int)gridDim.x;
  int s = blockIdx.x;
  if (s >= nstrip) return;

  B8u afA[4], hfA[4], afB[4], hfB[4];
  float holdA[4], degA[4], holdB[4], degB[4];
  gru_load(c, s, afA, hfA, holdA, degA);

  while (true) {
    int ns = s + G;                 // body A: compute A-bufs, prefetch into B
    bool more = ns < nstrip;
    if (more) gru_load(c, ns, afB, hfB, holdB, degB);
    gru_compute(c, s, afA, hfA, holdA, degA, bw, bh);
    if (!more) break;
    s = ns;
    ns = s + G;                     // body B: compute B-bufs, prefetch into A
    more = ns < nstrip;
    if (more) gru_load(c, ns, afA, hfA, holdA, degA);
    gru_compute(c, s, afB, hfB, holdB, degB, bw, bh);
    if (!more) break;
    s = ns;
  }
}

// ---- per-graph counts from SORTED gid: binary search, no atomics
__global__ __launch_bounds__(64) void k_bounds(const int* __restrict__ gid,
                                               int* __restrict__ cnt, int N, int G) {
  int g = threadIdx.x;
  if (g >= G) return;
  int lo = 0, hi = N;
  while (lo < hi) { int mid = (lo + hi) >> 1; if (gid[mid] < g) lo = mid + 1; else hi = mid; }
  int lb0 = lo;
  lo = 0; hi = N;
  int g1 = g + 1;
  while (lo < hi) { int mid = (lo + hi) >> 1; if (gid[mid] < g1) lo = mid + 1; else hi = mid; }
  cnt[g] = lo - lb0;
}

// ---- pooling: graph_ids sorted -> run-length accumulate, few atomics
#define POOL_CHUNK 96
__global__ __launch_bounds__(128) void k_pool(const ushort* __restrict__ hb,
                                              const int* __restrict__ gid,
                                              float* __restrict__ hg, int N) {
  int d = threadIdx.x;
  int start = blockIdx.x * POOL_CHUNK;
  if (start >= N) return;
  int end = min(start + POOL_CHUNK, N);
  float acc = 0.f;
  int g = gid[start];
  for (int n = start; n < end; ++n) {
    int gn = gid[n];
    if (gn != g) { unsafeAtomicAdd(&hg[g * HID + d], acc); acc = 0.f; g = gn; }
    acc += fmaxf(bf2f(hb[(size_t)n * HID + d]), 0.f);   // relu
  }
  unsafeAtomicAdd(&hg[g * HID + d], acc);
}

__global__ __launch_bounds__(640) void k_cls(const float* __restrict__ hg,
                                             const int* __restrict__ cnt,
                                             const float* __restrict__ Wc,
                                             const float* __restrict__ bc,
                                             float* __restrict__ out, int G) {
  int t = threadIdx.x;
  if (t >= G * 10) return;
  int g = t / 10, c = t % 10;
  float inv = 1.f / fmaxf((float)cnt[g], 1.f);
  float acc = 0.f;
  for (int d = 0; d < HID; ++d) acc = fmaf(hg[g * HID + d], Wc[c * HID + d], acc);
  out[t] = acc * inv + bc[c];
}

extern "C" void kernel_launch(void* const* d_in, const int* in_sizes, int n_in,
                              void* d_out, int out_size, void* d_ws, size_t ws_size,
                              hipStream_t stream) {
  const int N = in_sizes[0];
  const int E = in_sizes[9];
  const float* m    = (const float*)d_in[0];
  const float* W_e  = (const float*)d_in[1];
  const float* b_e  = (const float*)d_in[2];
  const float* W_ih = (const float*)d_in[3];
  const float* b_ih = (const float*)d_in[4];
  const float* W_hh = (const float*)d_in[5];
  const float* b_hh = (const float*)d_in[6];
  const float* W_cls = (const float*)d_in[7];
  const float* b_cls = (const float*)d_in[8];
  const int* src = (const int*)d_in[9];
  const int* dst = (const int*)d_in[10];
  const int* gid = (const int*)d_in[11];
  const int G = out_size / 10;
  float* out = (float*)d_out;

  size_t off = 0;
  auto alloc = [&](size_t b) {
    char* p = (char*)d_ws + off;
    off += (b + 255) & ~(size_t)255;
    return (void*)p;
  };
  ushort* hb0    = (ushort*)alloc((size_t)N * HID * 2);
  ushort* hb1    = (ushort*)alloc((size_t)N * HID * 2);
  ushort* hs16   = (ushort*)alloc((size_t)N * HID * 2);
  int*    deg    = (int*)   alloc((size_t)N * 4);
  int*    rowptr = (int*)   alloc((size_t)(N + 1) * 4);
  int*    csrc   = (int*)   alloc((size_t)E * 4);
  uint*   ebuf   = (uint*)  alloc((size_t)E * 4);
  int*    bhist  = (int*)   alloc((size_t)MAXBUK * 4);
  int*    bbase  = (int*)   alloc((size_t)(MAXBUK + 1) * 4);
  int*    gcur   = (int*)   alloc((size_t)MAXBUK * 4);
  ushort* Wcomb  = (ushort*)alloc((size_t)G3 * HID * 2);
  ushort* Whh16  = (ushort*)alloc((size_t)G3 * HID * 2);
  float*  bvec   = (float*) alloc((size_t)G3 * 4);
  float*  hg     = (float*) alloc((size_t)G * HID * 4);
  int*    cnt    = (int*)   alloc((size_t)G * 4);
  if (off > ws_size) return;   // workspace too small -> visible failure

  const int NBUK = (N + BNODES - 1) >> BSHIFT;   // 196 at N=100k (<= MAXBUK)

  k_weights<<<2 * G3, HID, 0, stream>>>(W_e, b_e, W_ih, W_hh, Wcomb, Whh16, bvec);
  hipMemsetAsync(bhist, 0, (size_t)MAXBUK * 4, stream);
  k_bh<<<256, 256, 0, stream>>>(dst, bhist, E);
  k_bsc<<<1, MAXBUK, 0, stream>>>(bhist, bbase, gcur, rowptr, E, N);
  k_part<<<(E + PART_EPB - 1) / PART_EPB, 256, 0, stream>>>(src, dst, gcur, ebuf, E);
  k_fill2<<<NBUK, 256, 0, stream>>>(ebuf, bbase, csrc, rowptr, deg, N);
  k_init<<<(N * HID + 255) / 256, 256, 0, stream>>>(m, hb0, N);

  ushort* hbc = hb0;
  ushort* hbn = hb1;
  const int nstrip = N >> 4;
  const int gather_blocks = 8 * ((nstrip + 7) / 8) * 4;
  const int gru_blocks = nstrip < 1024 ? nstrip : 1024;
  for (int s = 0; s < TSTEPS; ++s) {
    k_gather<<<gather_blocks, 256, 0, stream>>>(rowptr, csrc, hbc, hs16, N, nstrip);
    k_gru<<<gru_blocks, 512, 0, stream>>>(hs16, hbc, hbn, Wcomb, Whh16, bvec, b_ih, b_hh, deg, N);
    ushort* t = hbc; hbc = hbn; hbn = t;
  }

  hipMemsetAsync(hg, 0, (size_t)G * HID * 4, stream);
  k_bounds<<<1, 64, 0, stream>>>(gid, cnt, N, G);
  k_pool<<<(N + POOL_CHUNK - 1) / POOL_CHUNK, HID, 0, stream>>>(hbc, gid, hg, N);
  k_cls<<<1, 640, 0, stream>>>(hg, cnt, W_cls, b_cls, out, G);
}